// Round 5
// baseline (198.159 us; speedup 1.0000x reference)
//
#include <hip/hip_runtime.h>
#include <math.h>

#define VOCABN 100000
#define EMBED 300
#define BATCH 131072
#define NEG 10
#define RQ 20                    // uint4 chunks per padded fp8 row (320 B, 64B-aligned)

typedef float float2v __attribute__((ext_vector_type(2)));
typedef float float4v __attribute__((ext_vector_type(4)));

// ---------- fp8 helpers (gfx950 OCP e4m3 HW converters) ----------
// selector args must be compile-time constants -> template params

template <bool HI>
__device__ __forceinline__ float2v cvt2(unsigned int w) {
    return __builtin_amdgcn_cvt_pk_f32_fp8((int)w, HI);
}
template <bool HI>
__device__ __forceinline__ unsigned int pk2(unsigned int old, float a, float b) {
    return (unsigned int)__builtin_amdgcn_cvt_pk_fp8_f32(a, b, (int)old, HI);
}

// 16 fp8 (uint4) dotted against 8 packed float2 center regs, packed accumulate
__device__ __forceinline__ float2v dq8(const float2v* c, uint4 q, float2v acc) {
    acc += c[0] * cvt2<false>(q.x);
    acc += c[1] * cvt2<true >(q.x);
    acc += c[2] * cvt2<false>(q.y);
    acc += c[3] * cvt2<true >(q.y);
    acc += c[4] * cvt2<false>(q.z);
    acc += c[5] * cvt2<true >(q.z);
    acc += c[6] * cvt2<false>(q.w);
    acc += c[7] * cvt2<true >(q.w);
    return acc;
}

// unpack 16 fp8 -> 8 packed float2
__device__ __forceinline__ void unp8(uint4 q, float2v* f) {
    f[0] = cvt2<false>(q.x);
    f[1] = cvt2<true >(q.x);
    f[2] = cvt2<false>(q.y);
    f[3] = cvt2<true >(q.y);
    f[4] = cvt2<false>(q.z);
    f[5] = cvt2<true >(q.z);
    f[6] = cvt2<false>(q.w);
    f[7] = cvt2<true >(q.w);
}

// ---------- misc ----------

__device__ __forceinline__ float dot4(const float4 a, const float4 b) {
    return a.x * b.x + a.y * b.y + a.z * b.z + a.w * b.w;
}

__device__ __forceinline__ float lsig(float x) {
    float ax = fabsf(x);
    return fminf(x, 0.0f) - __logf(1.0f + __expf(-ax));
}

__device__ __forceinline__ float reduce16(float v) {
    v += __shfl_xor(v, 1);
    v += __shfl_xor(v, 2);
    v += __shfl_xor(v, 4);
    v += __shfl_xor(v, 8);
    return v;
}

__global__ void sgns_zero_acc(double* acc) { *acc = 0.0; }

__global__ void sgns_finalize(const double* __restrict__ acc, float* __restrict__ out) {
    *out = (float)(-(*acc) / (double)BATCH);
}

// ---------- fused f32 -> padded fp8 conversion for BOTH tables ----------
// rows padded to 320 B: elements 0..299 real, 300..319 zero.
// nontemporal f32 reads keep the dead source stream out of L3.

__global__ __launch_bounds__(256) void cvt_fp8_all(
    const float* __restrict__ srcA, const float* __restrict__ srcB,
    uint4* __restrict__ dstA, uint4* __restrict__ dstB)
{
    const int T = VOCABN * RQ;          // chunks per table
    const int total = 2 * T;
    const int stride = gridDim.x * blockDim.x;
    for (int i = blockIdx.x * blockDim.x + threadIdx.x; i < total; i += stride) {
        const int t = (i >= T);
        const int j = i - t * T;
        const int r = j / RQ;
        const int q = j - r * RQ;
        const float* src = t ? srcB : srcA;
        uint4* dst = t ? dstB : dstA;

        uint4 o = make_uint4(0u, 0u, 0u, 0u);
        if (q < 19) {
            const float4v* s = reinterpret_cast<const float4v*>(src + (size_t)r * EMBED + q * 16);
            float4v a = __builtin_nontemporal_load(s);
            float4v b = __builtin_nontemporal_load(s + 1);
            float4v c = __builtin_nontemporal_load(s + 2);
            float4v d = {0.f, 0.f, 0.f, 0.f};
            if (q < 18) d = __builtin_nontemporal_load(s + 3);  // q==18: 300..303 pad
            unsigned int w;
            w = pk2<false>(0, a[0], a[1]); o.x = pk2<true>(w, a[2], a[3]);
            w = pk2<false>(0, b[0], b[1]); o.y = pk2<true>(w, b[2], b[3]);
            w = pk2<false>(0, c[0], c[1]); o.z = pk2<true>(w, c[2], c[3]);
            w = pk2<false>(0, d[0], d[1]); o.w = pk2<true>(w, d[2], d[3]);
        }
        dst[(size_t)t * 0 + j + (size_t)0] = o;   // dst already table-selected; j indexes within table
    }
}

// ---------- fp8 gather kernel ----------
// 16-lane group per batch element; row = 20 uint4 (64B-aligned, 5 cachelines):
// main chunk = chunk[lane]; tail chunk = chunk[16 + (lane&3)] (chunks 16..19,
// chunk 19 is zero pad). Tail duplicates (lanes >= 4) are cancelled by zeroing
// the center-tail registers once per batch element — no per-row masking.

__global__ __launch_bounds__(256) void sgns_fp8(
    const int* __restrict__ center_words,
    const int* __restrict__ context_words,
    const int* __restrict__ neg_samples,
    const uint4* __restrict__ inQ,
    const uint4* __restrict__ outQ,
    double* __restrict__ acc)
{
    const int lane = threadIdx.x & 15;
    const int group = (blockIdx.x * blockDim.x + threadIdx.x) >> 4;
    const int nGroups = (gridDim.x * blockDim.x) >> 4;
    const int tq = 16 + (lane & 3);
    const float tmask = (lane < 4) ? 1.0f : 0.0f;

    float tsum = 0.0f;

    for (int b = group; b < BATCH; b += nGroups) {
        const int cw = center_words[b];
        const int xw = context_words[b];
        const int2* np = reinterpret_cast<const int2*>(neg_samples + (size_t)b * NEG);
        int2 q0 = np[0], q1 = np[1], q2 = np[2], q3 = np[3], q4 = np[4];
        int idx[11] = {xw, q0.x, q0.y, q1.x, q1.y, q2.x, q2.y, q3.x, q3.y, q4.x, q4.y};

        // center row -> 16 packed float2 (main 8 + tail 8; tail zeroed for lanes >= 4)
        const uint4* cp = inQ + (size_t)cw * RQ;
        uint4 cm = cp[lane];
        uint4 ct = cp[tq];
        float2v cf2[16];
        unp8(cm, cf2);
        unp8(ct, cf2 + 8);
        #pragma unroll
        for (int j = 8; j < 16; ++j) cf2[j] *= tmask;

        // 3-deep pipelined gather+dot over the 11 score rows
        float part[11];
        uint4 bm[3], bt[3];
        {
            const uint4* p0 = outQ + (size_t)idx[0] * RQ;
            bm[0] = p0[lane]; bt[0] = p0[tq];
            const uint4* p1 = outQ + (size_t)idx[1] * RQ;
            bm[1] = p1[lane]; bt[1] = p1[tq];
        }
        #pragma unroll
        for (int j = 0; j < 11; ++j) {
            if (j + 2 < 11) {
                const uint4* p = outQ + (size_t)idx[j + 2] * RQ;
                bm[(j + 2) % 3] = p[lane];
                bt[(j + 2) % 3] = p[tq];
            }
            float2v a2 = dq8(cf2, bm[j % 3], (float2v){0.f, 0.f});
            a2 = dq8(cf2 + 8, bt[j % 3], a2);
            part[j] = a2.x + a2.y;
        }

        #pragma unroll
        for (int j = 0; j < 11; ++j) part[j] = reduce16(part[j]);

        float loss = lsig(part[0]);
        #pragma unroll
        for (int j = 1; j < 11; ++j) loss += lsig(-part[j]);

        tsum += (lane == 0) ? loss : 0.0f;
    }

    float w = tsum;
    #pragma unroll
    for (int m = 1; m < 64; m <<= 1) w += __shfl_xor(w, m);

    __shared__ double ssum[4];
    const int wid = threadIdx.x >> 6;
    if ((threadIdx.x & 63) == 0) ssum[wid] = (double)w;
    __syncthreads();
    if (threadIdx.x == 0) {
        atomicAdd(acc, ssum[0] + ssum[1] + ssum[2] + ssum[3]);
    }
}

// ---------- f32 fallback (proven) ----------

__global__ __launch_bounds__(256) void sgns_f32(
    const int* __restrict__ center_words,
    const int* __restrict__ context_words,
    const int* __restrict__ neg_samples,
    const float* __restrict__ in_embed,
    const float* __restrict__ out_embed,
    double* __restrict__ acc)
{
    const int lane = threadIdx.x & 15;
    const int group = (blockIdx.x * blockDim.x + threadIdx.x) >> 4;
    const int nGroups = (gridDim.x * blockDim.x) >> 4;

    const float4* inE = reinterpret_cast<const float4*>(in_embed);
    const float4* outE = reinterpret_cast<const float4*>(out_embed);
    const int RU = EMBED / 4;
    const int TAIL = RU - 64;

    float tsum = 0.0f;

    for (int b = group; b < BATCH; b += nGroups) {
        const int c = center_words[b];
        const int ctx = context_words[b];

        const float4* crow = inE + (size_t)c * RU;
        float4 c0 = crow[lane + 0];
        float4 c1 = crow[lane + 16];
        float4 c2 = crow[lane + 32];
        float4 c3 = crow[lane + 48];
        float4 c4 = make_float4(0.f, 0.f, 0.f, 0.f);
        if (lane < TAIL) c4 = crow[lane + 64];

        const float4* xrow = outE + (size_t)ctx * RU;
        float p = dot4(c0, xrow[lane + 0])
                + dot4(c1, xrow[lane + 16])
                + dot4(c2, xrow[lane + 32])
                + dot4(c3, xrow[lane + 48]);
        if (lane < TAIL) p += dot4(c4, xrow[lane + 64]);
        p = reduce16(p);

        float loss = lsig(p);

        #pragma unroll
        for (int k = 0; k < NEG; ++k) {
            const int nk = neg_samples[b * NEG + k];
            const float4* nrow = outE + (size_t)nk * RU;
            float s = dot4(c0, nrow[lane + 0])
                    + dot4(c1, nrow[lane + 16])
                    + dot4(c2, nrow[lane + 32])
                    + dot4(c3, nrow[lane + 48]);
            if (lane < TAIL) s += dot4(c4, nrow[lane + 64]);
            s = reduce16(s);
            loss += lsig(-s);
        }

        tsum += (lane == 0) ? loss : 0.0f;
    }

    float w = tsum;
    #pragma unroll
    for (int m = 1; m < 64; m <<= 1) w += __shfl_xor(w, m);

    __shared__ double ssum[4];
    const int wid = threadIdx.x >> 6;
    if ((threadIdx.x & 63) == 0) ssum[wid] = (double)w;
    __syncthreads();
    if (threadIdx.x == 0) {
        atomicAdd(acc, ssum[0] + ssum[1] + ssum[2] + ssum[3]);
    }
}

// ---------- launch ----------

extern "C" void kernel_launch(void* const* d_in, const int* in_sizes, int n_in,
                              void* d_out, int out_size, void* d_ws, size_t ws_size,
                              hipStream_t stream) {
    const int* center = (const int*)d_in[0];
    const int* context = (const int*)d_in[1];
    const int* negs = (const int*)d_in[2];
    const float* inE = (const float*)d_in[3];
    const float* outE = (const float*)d_in[4];
    float* out = (float*)d_out;
    double* acc = (double*)d_ws;

    sgns_zero_acc<<<1, 1, 0, stream>>>(acc);

    const size_t TBL_BYTES = (size_t)VOCABN * RQ * 16;   // 32,000,000 per table
    const size_t need = 256 + 2 * TBL_BYTES;

    if (ws_size >= need) {
        uint4* inQ = (uint4*)((char*)d_ws + 256);
        uint4* outQ = (uint4*)((char*)d_ws + 256 + TBL_BYTES);
        cvt_fp8_all<<<4096, 256, 0, stream>>>(inE, outE, inQ, outQ);
        sgns_fp8<<<2048, 256, 0, stream>>>(center, context, negs,
                                           (const uint4*)inQ, (const uint4*)outQ, acc);
    } else {
        sgns_f32<<<2048, 256, 0, stream>>>(center, context, negs, inE, outE, acc);
    }

    sgns_finalize<<<1, 1, 0, stream>>>(acc, out);
}

// Round 6
// 192.973 us; speedup vs baseline: 1.0269x; 1.0269x over previous
//
#include <hip/hip_runtime.h>
#include <math.h>

#define VOCABN 100000
#define EMBED 300
#define BATCH 131072
#define NEG 10
#define RQ 19                    // uint4 chunks per padded fp8 row (304 B)

typedef float float2v __attribute__((ext_vector_type(2)));

// ---------- fp8 helpers (gfx950 OCP e4m3 HW converters) ----------
// selector args must be compile-time constants -> template params

template <bool HI>
__device__ __forceinline__ float2v cvt2(unsigned int w) {
    return __builtin_amdgcn_cvt_pk_f32_fp8((int)w, HI);
}
template <bool HI>
__device__ __forceinline__ unsigned int pk2(unsigned int old, float a, float b) {
    return (unsigned int)__builtin_amdgcn_cvt_pk_fp8_f32(a, b, (int)old, HI);
}

// dot of 16 center floats against 16 fp8 values packed in a uint4
__device__ __forceinline__ float dqf(const float* c, uint4 q) {
    float2v p;
    float s = 0.0f;
    p = cvt2<false>(q.x); s += c[0]  * p.x + c[1]  * p.y;
    p = cvt2<true >(q.x); s += c[2]  * p.x + c[3]  * p.y;
    p = cvt2<false>(q.y); s += c[4]  * p.x + c[5]  * p.y;
    p = cvt2<true >(q.y); s += c[6]  * p.x + c[7]  * p.y;
    p = cvt2<false>(q.z); s += c[8]  * p.x + c[9]  * p.y;
    p = cvt2<true >(q.z); s += c[10] * p.x + c[11] * p.y;
    p = cvt2<false>(q.w); s += c[12] * p.x + c[13] * p.y;
    p = cvt2<true >(q.w); s += c[14] * p.x + c[15] * p.y;
    return s;
}

// unpack 16 fp8 -> 16 floats
__device__ __forceinline__ void unp16(uint4 q, float* f) {
    float2v p;
    p = cvt2<false>(q.x); f[0]  = p.x; f[1]  = p.y;
    p = cvt2<true >(q.x); f[2]  = p.x; f[3]  = p.y;
    p = cvt2<false>(q.y); f[4]  = p.x; f[5]  = p.y;
    p = cvt2<true >(q.y); f[6]  = p.x; f[7]  = p.y;
    p = cvt2<false>(q.z); f[8]  = p.x; f[9]  = p.y;
    p = cvt2<true >(q.z); f[10] = p.x; f[11] = p.y;
    p = cvt2<false>(q.w); f[12] = p.x; f[13] = p.y;
    p = cvt2<true >(q.w); f[14] = p.x; f[15] = p.y;
}

// ---------- misc ----------

__device__ __forceinline__ float dot4(const float4 a, const float4 b) {
    return a.x * b.x + a.y * b.y + a.z * b.z + a.w * b.w;
}

__device__ __forceinline__ float lsig(float x) {
    float ax = fabsf(x);
    return fminf(x, 0.0f) - __logf(1.0f + __expf(-ax));
}

__device__ __forceinline__ float reduce16(float v) {
    v += __shfl_xor(v, 1);
    v += __shfl_xor(v, 2);
    v += __shfl_xor(v, 4);
    v += __shfl_xor(v, 8);
    return v;
}

__global__ void sgns_zero_acc(double* acc) { *acc = 0.0; }

__global__ void sgns_finalize(const double* __restrict__ acc, float* __restrict__ out) {
    *out = (float)(-(*acc) / (double)BATCH);
}

// ---------- f32 -> padded fp8 table conversion (r4-proven form) ----------
// output rows: 19 uint4 (304 B): elements 0..299 + 4 zero pad bytes

__global__ __launch_bounds__(256) void cvt_fp8(const float* __restrict__ src,
                                               uint4* __restrict__ dst, int nrows) {
    const int total = nrows * RQ;
    const int stride = gridDim.x * blockDim.x;
    for (int i = blockIdx.x * blockDim.x + threadIdx.x; i < total; i += stride) {
        int r = i / RQ;
        int q = i - r * RQ;
        const float4* s = reinterpret_cast<const float4*>(src + (size_t)r * EMBED + q * 16);
        float4 a = s[0], b = s[1], c = s[2];
        float4 d = make_float4(0.f, 0.f, 0.f, 0.f);
        if (q != RQ - 1) d = s[3];          // last chunk: elements 300..303 are pad -> 0
        uint4 o;
        unsigned int w;
        w = pk2<false>(0, a.x, a.y); o.x = pk2<true>(w, a.z, a.w);
        w = pk2<false>(0, b.x, b.y); o.y = pk2<true>(w, b.z, b.w);
        w = pk2<false>(0, c.x, c.y); o.z = pk2<true>(w, c.z, c.w);
        w = pk2<false>(0, d.x, d.y); o.w = pk2<true>(w, d.z, d.w);
        dst[i] = o;
    }
}

// ---------- fp8 gather kernel (r4-proven form; grid gives 1 element/group) ----------

__global__ __launch_bounds__(256) void sgns_fp8(
    const int* __restrict__ center_words,
    const int* __restrict__ context_words,
    const int* __restrict__ neg_samples,
    const uint4* __restrict__ inQ,
    const uint4* __restrict__ outQ,
    double* __restrict__ acc)
{
    const int lane = threadIdx.x & 15;
    const int group = (blockIdx.x * blockDim.x + threadIdx.x) >> 4;
    const int nGroups = (gridDim.x * blockDim.x) >> 4;
    const int tl = (lane < 3) ? lane : 0;
    const float tmask = (lane < 3) ? 1.0f : 0.0f;

    float tsum = 0.0f;

    for (int b = group; b < BATCH; b += nGroups) {
        const int cw = center_words[b];
        const int xw = context_words[b];
        const int2* np = reinterpret_cast<const int2*>(neg_samples + (size_t)b * NEG);
        int2 q0 = np[0], q1 = np[1], q2 = np[2], q3 = np[3], q4 = np[4];
        int idx[11] = {xw, q0.x, q0.y, q1.x, q1.y, q2.x, q2.y, q3.x, q3.y, q4.x, q4.y};

        // center row -> 32 floats (tail half masked for lanes >= 3)
        const uint4* cp = inQ + (size_t)cw * RQ;
        uint4 cm = cp[lane];
        uint4 ct = cp[16 + tl];
        float cf[32];
        unp16(cm, cf);
        unp16(ct, cf + 16);
        #pragma unroll
        for (int j = 16; j < 32; ++j) cf[j] *= tmask;

        // 3-deep pipelined gather+dot over the 11 score rows
        float part[11];
        uint4 bm[3], bt[3];
        {
            const uint4* p0 = outQ + (size_t)idx[0] * RQ;
            bm[0] = p0[lane]; bt[0] = p0[16 + tl];
            const uint4* p1 = outQ + (size_t)idx[1] * RQ;
            bm[1] = p1[lane]; bt[1] = p1[16 + tl];
        }
        #pragma unroll
        for (int j = 0; j < 11; ++j) {
            if (j + 2 < 11) {
                const uint4* p = outQ + (size_t)idx[j + 2] * RQ;
                bm[(j + 2) % 3] = p[lane];
                bt[(j + 2) % 3] = p[16 + tl];
            }
            part[j] = dqf(cf, bm[j % 3]) + dqf(cf + 16, bt[j % 3]);
        }

        #pragma unroll
        for (int j = 0; j < 11; ++j) part[j] = reduce16(part[j]);

        float loss = lsig(part[0]);
        #pragma unroll
        for (int j = 1; j < 11; ++j) loss += lsig(-part[j]);

        tsum += (lane == 0) ? loss : 0.0f;
    }

    float w = tsum;
    #pragma unroll
    for (int m = 1; m < 64; m <<= 1) w += __shfl_xor(w, m);

    __shared__ double ssum[4];
    const int wid = threadIdx.x >> 6;
    if ((threadIdx.x & 63) == 0) ssum[wid] = (double)w;
    __syncthreads();
    if (threadIdx.x == 0) {
        atomicAdd(acc, ssum[0] + ssum[1] + ssum[2] + ssum[3]);
    }
}

// ---------- f32 fallback (proven) ----------

__global__ __launch_bounds__(256) void sgns_f32(
    const int* __restrict__ center_words,
    const int* __restrict__ context_words,
    const int* __restrict__ neg_samples,
    const float* __restrict__ in_embed,
    const float* __restrict__ out_embed,
    double* __restrict__ acc)
{
    const int lane = threadIdx.x & 15;
    const int group = (blockIdx.x * blockDim.x + threadIdx.x) >> 4;
    const int nGroups = (gridDim.x * blockDim.x) >> 4;

    const float4* inE = reinterpret_cast<const float4*>(in_embed);
    const float4* outE = reinterpret_cast<const float4*>(out_embed);
    const int RU = EMBED / 4;
    const int TAIL = RU - 64;

    float tsum = 0.0f;

    for (int b = group; b < BATCH; b += nGroups) {
        const int c = center_words[b];
        const int ctx = context_words[b];

        const float4* crow = inE + (size_t)c * RU;
        float4 c0 = crow[lane + 0];
        float4 c1 = crow[lane + 16];
        float4 c2 = crow[lane + 32];
        float4 c3 = crow[lane + 48];
        float4 c4 = make_float4(0.f, 0.f, 0.f, 0.f);
        if (lane < TAIL) c4 = crow[lane + 64];

        const float4* xrow = outE + (size_t)ctx * RU;
        float p = dot4(c0, xrow[lane + 0])
                + dot4(c1, xrow[lane + 16])
                + dot4(c2, xrow[lane + 32])
                + dot4(c3, xrow[lane + 48]);
        if (lane < TAIL) p += dot4(c4, xrow[lane + 64]);
        p = reduce16(p);

        float loss = lsig(p);

        #pragma unroll
        for (int k = 0; k < NEG; ++k) {
            const int nk = neg_samples[b * NEG + k];
            const float4* nrow = outE + (size_t)nk * RU;
            float s = dot4(c0, nrow[lane + 0])
                    + dot4(c1, nrow[lane + 16])
                    + dot4(c2, nrow[lane + 32])
                    + dot4(c3, nrow[lane + 48]);
            if (lane < TAIL) s += dot4(c4, nrow[lane + 64]);
            s = reduce16(s);
            loss += lsig(-s);
        }

        tsum += (lane == 0) ? loss : 0.0f;
    }

    float w = tsum;
    #pragma unroll
    for (int m = 1; m < 64; m <<= 1) w += __shfl_xor(w, m);

    __shared__ double ssum[4];
    const int wid = threadIdx.x >> 6;
    if ((threadIdx.x & 63) == 0) ssum[wid] = (double)w;
    __syncthreads();
    if (threadIdx.x == 0) {
        atomicAdd(acc, ssum[0] + ssum[1] + ssum[2] + ssum[3]);
    }
}

// ---------- launch ----------

extern "C" void kernel_launch(void* const* d_in, const int* in_sizes, int n_in,
                              void* d_out, int out_size, void* d_ws, size_t ws_size,
                              hipStream_t stream) {
    const int* center = (const int*)d_in[0];
    const int* context = (const int*)d_in[1];
    const int* negs = (const int*)d_in[2];
    const float* inE = (const float*)d_in[3];
    const float* outE = (const float*)d_in[4];
    float* out = (float*)d_out;
    double* acc = (double*)d_ws;

    sgns_zero_acc<<<1, 1, 0, stream>>>(acc);

    const size_t TBL_BYTES = (size_t)VOCABN * RQ * 16;   // 30,400,000 per table
    const size_t need = 256 + 2 * TBL_BYTES;

    if (ws_size >= need) {
        uint4* inQ = (uint4*)((char*)d_ws + 256);
        uint4* outQ = (uint4*)((char*)d_ws + 256 + TBL_BYTES);
        cvt_fp8<<<4096, 256, 0, stream>>>(inE, inQ, VOCABN);
        cvt_fp8<<<4096, 256, 0, stream>>>(outE, outQ, VOCABN);
        // one batch element per 16-lane group: 8192 blocks * 256 thr / 16 = 131072 groups
        sgns_fp8<<<8192, 256, 0, stream>>>(center, context, negs,
                                           (const uint4*)inQ, (const uint4*)outQ, acc);
    } else {
        sgns_f32<<<2048, 256, 0, stream>>>(center, context, negs, inE, outE, acc);
    }

    sgns_finalize<<<1, 1, 0, stream>>>(acc, out);
}

// Round 7
// 151.390 us; speedup vs baseline: 1.3089x; 1.2747x over previous
//
#include <hip/hip_runtime.h>
#include <math.h>

#define VOCABN 100000
#define EMBED 300
#define BATCH 131072
#define NEG 10
#define RQ 19                    // uint4 chunks per padded fp8 row (304 B)
#define PD 5                     // row-pipeline depth (lookahead)

typedef float float2v __attribute__((ext_vector_type(2)));

// ---------- fp8 helpers (gfx950 OCP e4m3 HW converters) ----------
// selector args must be compile-time constants -> template params

template <bool HI>
__device__ __forceinline__ float2v cvt2(unsigned int w) {
    return __builtin_amdgcn_cvt_pk_f32_fp8((int)w, HI);
}
template <bool HI>
__device__ __forceinline__ unsigned int pk2(unsigned int old, float a, float b) {
    return (unsigned int)__builtin_amdgcn_cvt_pk_fp8_f32(a, b, (int)old, HI);
}

// dot of 16 center floats against 16 fp8 values packed in a uint4
__device__ __forceinline__ float dqf(const float* c, uint4 q) {
    float2v p;
    float s = 0.0f;
    p = cvt2<false>(q.x); s += c[0]  * p.x + c[1]  * p.y;
    p = cvt2<true >(q.x); s += c[2]  * p.x + c[3]  * p.y;
    p = cvt2<false>(q.y); s += c[4]  * p.x + c[5]  * p.y;
    p = cvt2<true >(q.y); s += c[6]  * p.x + c[7]  * p.y;
    p = cvt2<false>(q.z); s += c[8]  * p.x + c[9]  * p.y;
    p = cvt2<true >(q.z); s += c[10] * p.x + c[11] * p.y;
    p = cvt2<false>(q.w); s += c[12] * p.x + c[13] * p.y;
    p = cvt2<true >(q.w); s += c[14] * p.x + c[15] * p.y;
    return s;
}

// unpack 16 fp8 -> 16 floats
__device__ __forceinline__ void unp16(uint4 q, float* f) {
    float2v p;
    p = cvt2<false>(q.x); f[0]  = p.x; f[1]  = p.y;
    p = cvt2<true >(q.x); f[2]  = p.x; f[3]  = p.y;
    p = cvt2<false>(q.y); f[4]  = p.x; f[5]  = p.y;
    p = cvt2<true >(q.y); f[6]  = p.x; f[7]  = p.y;
    p = cvt2<false>(q.z); f[8]  = p.x; f[9]  = p.y;
    p = cvt2<true >(q.z); f[10] = p.x; f[11] = p.y;
    p = cvt2<false>(q.w); f[12] = p.x; f[13] = p.y;
    p = cvt2<true >(q.w); f[14] = p.x; f[15] = p.y;
}

// ---------- misc ----------

__device__ __forceinline__ float dot4(const float4 a, const float4 b) {
    return a.x * b.x + a.y * b.y + a.z * b.z + a.w * b.w;
}

__device__ __forceinline__ float lsig(float x) {
    float ax = fabsf(x);
    return fminf(x, 0.0f) - __logf(1.0f + __expf(-ax));
}

__device__ __forceinline__ float reduce16(float v) {
    v += __shfl_xor(v, 1);
    v += __shfl_xor(v, 2);
    v += __shfl_xor(v, 4);
    v += __shfl_xor(v, 8);
    return v;
}

__global__ void sgns_zero_acc(double* acc) { *acc = 0.0; }

__global__ void sgns_finalize(const double* __restrict__ acc, float* __restrict__ out) {
    *out = (float)(-(*acc) / (double)BATCH);
}

// ---------- f32 -> padded fp8 table conversion (r4-proven form) ----------
// output rows: 19 uint4 (304 B): elements 0..299 + 4 zero pad bytes

__global__ __launch_bounds__(256) void cvt_fp8(const float* __restrict__ src,
                                               uint4* __restrict__ dst, int nrows) {
    const int total = nrows * RQ;
    const int stride = gridDim.x * blockDim.x;
    for (int i = blockIdx.x * blockDim.x + threadIdx.x; i < total; i += stride) {
        int r = i / RQ;
        int q = i - r * RQ;
        const float4* s = reinterpret_cast<const float4*>(src + (size_t)r * EMBED + q * 16);
        float4 a = s[0], b = s[1], c = s[2];
        float4 d = make_float4(0.f, 0.f, 0.f, 0.f);
        if (q != RQ - 1) d = s[3];          // last chunk: elements 300..303 are pad -> 0
        uint4 o;
        unsigned int w;
        w = pk2<false>(0, a.x, a.y); o.x = pk2<true>(w, a.z, a.w);
        w = pk2<false>(0, b.x, b.y); o.y = pk2<true>(w, b.z, b.w);
        w = pk2<false>(0, c.x, c.y); o.z = pk2<true>(w, c.z, c.w);
        w = pk2<false>(0, d.x, d.y); o.w = pk2<true>(w, d.z, d.w);
        dst[i] = o;
    }
}

// ---------- fp8 gather kernel (r4 structure, 5-deep row pipeline) ----------

__global__ __launch_bounds__(256) void sgns_fp8(
    const int* __restrict__ center_words,
    const int* __restrict__ context_words,
    const int* __restrict__ neg_samples,
    const uint4* __restrict__ inQ,
    const uint4* __restrict__ outQ,
    double* __restrict__ acc)
{
    const int lane = threadIdx.x & 15;
    const int group = (blockIdx.x * blockDim.x + threadIdx.x) >> 4;
    const int nGroups = (gridDim.x * blockDim.x) >> 4;
    const int tl = (lane < 3) ? lane : 0;
    const float tmask = (lane < 3) ? 1.0f : 0.0f;

    float tsum = 0.0f;

    for (int b = group; b < BATCH; b += nGroups) {
        const int cw = center_words[b];
        const int xw = context_words[b];
        const int2* np = reinterpret_cast<const int2*>(neg_samples + (size_t)b * NEG);
        int2 q0 = np[0], q1 = np[1], q2 = np[2], q3 = np[3], q4 = np[4];
        int idx[11] = {xw, q0.x, q0.y, q1.x, q1.y, q2.x, q2.y, q3.x, q3.y, q4.x, q4.y};

        // center row -> 32 floats (tail half masked for lanes >= 3)
        const uint4* cp = inQ + (size_t)cw * RQ;
        uint4 cm = cp[lane];
        uint4 ct = cp[16 + tl];
        float cf[32];
        unp16(cm, cf);
        unp16(ct, cf + 16);
        #pragma unroll
        for (int j = 16; j < 32; ++j) cf[j] *= tmask;

        // PD-deep pipelined gather+dot over the 11 score rows
        float part[11];
        uint4 bm[PD], bt[PD];
        #pragma unroll
        for (int j = 0; j < PD - 1; ++j) {
            const uint4* p = outQ + (size_t)idx[j] * RQ;
            bm[j] = p[lane]; bt[j] = p[16 + tl];
        }
        #pragma unroll
        for (int j = 0; j < 11; ++j) {
            if (j + PD - 1 < 11) {
                const uint4* p = outQ + (size_t)idx[j + PD - 1] * RQ;
                bm[(j + PD - 1) % PD] = p[lane];
                bt[(j + PD - 1) % PD] = p[16 + tl];
            }
            part[j] = dqf(cf, bm[j % PD]) + dqf(cf + 16, bt[j % PD]);
        }

        #pragma unroll
        for (int j = 0; j < 11; ++j) part[j] = reduce16(part[j]);

        float loss = lsig(part[0]);
        #pragma unroll
        for (int j = 1; j < 11; ++j) loss += lsig(-part[j]);

        tsum += (lane == 0) ? loss : 0.0f;
    }

    float w = tsum;
    #pragma unroll
    for (int m = 1; m < 64; m <<= 1) w += __shfl_xor(w, m);

    __shared__ double ssum[4];
    const int wid = threadIdx.x >> 6;
    if ((threadIdx.x & 63) == 0) ssum[wid] = (double)w;
    __syncthreads();
    if (threadIdx.x == 0) {
        atomicAdd(acc, ssum[0] + ssum[1] + ssum[2] + ssum[3]);
    }
}

// ---------- f32 fallback (proven) ----------

__global__ __launch_bounds__(256) void sgns_f32(
    const int* __restrict__ center_words,
    const int* __restrict__ context_words,
    const int* __restrict__ neg_samples,
    const float* __restrict__ in_embed,
    const float* __restrict__ out_embed,
    double* __restrict__ acc)
{
    const int lane = threadIdx.x & 15;
    const int group = (blockIdx.x * blockDim.x + threadIdx.x) >> 4;
    const int nGroups = (gridDim.x * blockDim.x) >> 4;

    const float4* inE = reinterpret_cast<const float4*>(in_embed);
    const float4* outE = reinterpret_cast<const float4*>(out_embed);
    const int RU = EMBED / 4;
    const int TAIL = RU - 64;

    float tsum = 0.0f;

    for (int b = group; b < BATCH; b += nGroups) {
        const int c = center_words[b];
        const int ctx = context_words[b];

        const float4* crow = inE + (size_t)c * RU;
        float4 c0 = crow[lane + 0];
        float4 c1 = crow[lane + 16];
        float4 c2 = crow[lane + 32];
        float4 c3 = crow[lane + 48];
        float4 c4 = make_float4(0.f, 0.f, 0.f, 0.f);
        if (lane < TAIL) c4 = crow[lane + 64];

        const float4* xrow = outE + (size_t)ctx * RU;
        float p = dot4(c0, xrow[lane + 0])
                + dot4(c1, xrow[lane + 16])
                + dot4(c2, xrow[lane + 32])
                + dot4(c3, xrow[lane + 48]);
        if (lane < TAIL) p += dot4(c4, xrow[lane + 64]);
        p = reduce16(p);

        float loss = lsig(p);

        #pragma unroll
        for (int k = 0; k < NEG; ++k) {
            const int nk = neg_samples[b * NEG + k];
            const float4* nrow = outE + (size_t)nk * RU;
            float s = dot4(c0, nrow[lane + 0])
                    + dot4(c1, nrow[lane + 16])
                    + dot4(c2, nrow[lane + 32])
                    + dot4(c3, nrow[lane + 48]);
            if (lane < TAIL) s += dot4(c4, nrow[lane + 64]);
            s = reduce16(s);
            loss += lsig(-s);
        }

        tsum += (lane == 0) ? loss : 0.0f;
    }

    float w = tsum;
    #pragma unroll
    for (int m = 1; m < 64; m <<= 1) w += __shfl_xor(w, m);

    __shared__ double ssum[4];
    const int wid = threadIdx.x >> 6;
    if ((threadIdx.x & 63) == 0) ssum[wid] = (double)w;
    __syncthreads();
    if (threadIdx.x == 0) {
        atomicAdd(acc, ssum[0] + ssum[1] + ssum[2] + ssum[3]);
    }
}

// ---------- launch ----------

extern "C" void kernel_launch(void* const* d_in, const int* in_sizes, int n_in,
                              void* d_out, int out_size, void* d_ws, size_t ws_size,
                              hipStream_t stream) {
    const int* center = (const int*)d_in[0];
    const int* context = (const int*)d_in[1];
    const int* negs = (const int*)d_in[2];
    const float* inE = (const float*)d_in[3];
    const float* outE = (const float*)d_in[4];
    float* out = (float*)d_out;
    double* acc = (double*)d_ws;

    sgns_zero_acc<<<1, 1, 0, stream>>>(acc);

    const size_t TBL_BYTES = (size_t)VOCABN * RQ * 16;   // 30,400,000 per table
    const size_t need = 256 + 2 * TBL_BYTES;

    if (ws_size >= need) {
        uint4* inQ = (uint4*)((char*)d_ws + 256);
        uint4* outQ = (uint4*)((char*)d_ws + 256 + TBL_BYTES);
        cvt_fp8<<<4096, 256, 0, stream>>>(inE, inQ, VOCABN);
        cvt_fp8<<<4096, 256, 0, stream>>>(outE, outQ, VOCABN);
        // 2048 blocks -> 32768 groups, 4 batch elems each (r4-proven config)
        sgns_fp8<<<2048, 256, 0, stream>>>(center, context, negs,
                                           (const uint4*)inQ, (const uint4*)outQ, acc);
    } else {
        sgns_f32<<<2048, 256, 0, stream>>>(center, context, negs, inE, outE, acc);
    }

    sgns_finalize<<<1, 1, 0, stream>>>(acc, out);
}

// Round 8
// 151.107 us; speedup vs baseline: 1.3114x; 1.0019x over previous
//
#include <hip/hip_runtime.h>
#include <math.h>

#define VOCABN 100000
#define EMBED 300
#define BATCH 131072
#define NEG 10
#define PD 3                     // row-pipeline depth (r4-proven)
// split fp8 layout: main = 16 uint4 (elems 0..255, 256B aligned rows),
//                   tail = 4 uint4 (elems 256..299 + pad, 64B rows)

typedef float float2v __attribute__((ext_vector_type(2)));

// ---------- fp8 helpers (gfx950 OCP e4m3 HW converters) ----------

template <bool HI>
__device__ __forceinline__ float2v cvt2(unsigned int w) {
    return __builtin_amdgcn_cvt_pk_f32_fp8((int)w, HI);
}
template <bool HI>
__device__ __forceinline__ unsigned int pk2(unsigned int old, float a, float b) {
    return (unsigned int)__builtin_amdgcn_cvt_pk_fp8_f32(a, b, (int)old, HI);
}

// dot of 16 center floats against 16 fp8 values packed in a uint4
__device__ __forceinline__ float dqf(const float* c, uint4 q) {
    float2v p;
    float s = 0.0f;
    p = cvt2<false>(q.x); s += c[0]  * p.x + c[1]  * p.y;
    p = cvt2<true >(q.x); s += c[2]  * p.x + c[3]  * p.y;
    p = cvt2<false>(q.y); s += c[4]  * p.x + c[5]  * p.y;
    p = cvt2<true >(q.y); s += c[6]  * p.x + c[7]  * p.y;
    p = cvt2<false>(q.z); s += c[8]  * p.x + c[9]  * p.y;
    p = cvt2<true >(q.z); s += c[10] * p.x + c[11] * p.y;
    p = cvt2<false>(q.w); s += c[12] * p.x + c[13] * p.y;
    p = cvt2<true >(q.w); s += c[14] * p.x + c[15] * p.y;
    return s;
}

// unpack 16 fp8 -> 16 floats
__device__ __forceinline__ void unp16(uint4 q, float* f) {
    float2v p;
    p = cvt2<false>(q.x); f[0]  = p.x; f[1]  = p.y;
    p = cvt2<true >(q.x); f[2]  = p.x; f[3]  = p.y;
    p = cvt2<false>(q.y); f[4]  = p.x; f[5]  = p.y;
    p = cvt2<true >(q.y); f[6]  = p.x; f[7]  = p.y;
    p = cvt2<false>(q.z); f[8]  = p.x; f[9]  = p.y;
    p = cvt2<true >(q.z); f[10] = p.x; f[11] = p.y;
    p = cvt2<false>(q.w); f[12] = p.x; f[13] = p.y;
    p = cvt2<true >(q.w); f[14] = p.x; f[15] = p.y;
}

// ---------- misc ----------

__device__ __forceinline__ float dot4(const float4 a, const float4 b) {
    return a.x * b.x + a.y * b.y + a.z * b.z + a.w * b.w;
}

__device__ __forceinline__ float lsig(float x) {
    float ax = fabsf(x);
    return fminf(x, 0.0f) - __logf(1.0f + __expf(-ax));
}

__device__ __forceinline__ float reduce16(float v) {
    v += __shfl_xor(v, 1);
    v += __shfl_xor(v, 2);
    v += __shfl_xor(v, 4);
    v += __shfl_xor(v, 8);
    return v;
}

__global__ void sgns_zero_acc(double* acc) { *acc = 0.0; }

__global__ void sgns_finalize(const double* __restrict__ acc, float* __restrict__ out) {
    *out = (float)(-(*acc) / (double)BATCH);
}

// ---------- f32 -> split fp8 table conversion ----------
// main rows: 16 uint4 (elems 0..255); tail rows: 4 uint4 (elems 256..299, rest 0)

__global__ __launch_bounds__(256) void cvt_fp8s(const float* __restrict__ src,
                                                uint4* __restrict__ mainT,
                                                uint4* __restrict__ tailT, int nrows) {
    const int total = nrows * 20;
    const int stride = gridDim.x * blockDim.x;
    for (int i = blockIdx.x * blockDim.x + threadIdx.x; i < total; i += stride) {
        const int r = i / 20;
        const int q = i - r * 20;
        if (q < 16) {
            const float4* s = reinterpret_cast<const float4*>(src + (size_t)r * EMBED + q * 16);
            float4 a = s[0], b = s[1], c = s[2], d = s[3];
            uint4 o;
            unsigned int w;
            w = pk2<false>(0, a.x, a.y); o.x = pk2<true>(w, a.z, a.w);
            w = pk2<false>(0, b.x, b.y); o.y = pk2<true>(w, b.z, b.w);
            w = pk2<false>(0, c.x, c.y); o.z = pk2<true>(w, c.z, c.w);
            w = pk2<false>(0, d.x, d.y); o.w = pk2<true>(w, d.z, d.w);
            mainT[(size_t)r * 16 + q] = o;
        } else {
            const int t = q - 16;
            uint4 o = make_uint4(0u, 0u, 0u, 0u);
            if (t < 3) {                      // elems 256 + t*16 .. +15
                const float4* s = reinterpret_cast<const float4*>(src + (size_t)r * EMBED + 256 + t * 16);
                float4 a = s[0], b = s[1], c = s[2];
                float4 d = make_float4(0.f, 0.f, 0.f, 0.f);
                if (t < 2) d = s[3];          // t==2: elems 300..303 are pad -> 0
                unsigned int w;
                w = pk2<false>(0, a.x, a.y); o.x = pk2<true>(w, a.z, a.w);
                w = pk2<false>(0, b.x, b.y); o.y = pk2<true>(w, b.z, b.w);
                w = pk2<false>(0, c.x, c.y); o.z = pk2<true>(w, c.z, c.w);
                w = pk2<false>(0, d.x, d.y); o.w = pk2<true>(w, d.z, d.w);
            }
            tailT[(size_t)r * 4 + t] = o;
        }
    }
}

// ---------- fp8 gather kernel (r4 structure, split tables) ----------
// 16-lane group per batch element. main chunk = mainT[row*16 + lane] (4 aligned
// lines/row); tail chunk = tailT[row*4 + tl], tl clamps lanes>=3 to chunk 0
// (same line, broadcast). Tail duplicates cancelled by zeroed center-tail regs.

__global__ __launch_bounds__(256) void sgns_fp8(
    const int* __restrict__ center_words,
    const int* __restrict__ context_words,
    const int* __restrict__ neg_samples,
    const uint4* __restrict__ inM,  const uint4* __restrict__ inT,
    const uint4* __restrict__ outM, const uint4* __restrict__ outT,
    double* __restrict__ acc)
{
    const int lane = threadIdx.x & 15;
    const int group = (blockIdx.x * blockDim.x + threadIdx.x) >> 4;
    const int nGroups = (gridDim.x * blockDim.x) >> 4;
    const int tl = (lane < 3) ? lane : 0;
    const float tmask = (lane < 3) ? 1.0f : 0.0f;

    float tsum = 0.0f;

    for (int b = group; b < BATCH; b += nGroups) {
        const int cw = center_words[b];
        const int xw = context_words[b];
        const int2* np = reinterpret_cast<const int2*>(neg_samples + (size_t)b * NEG);
        int2 q0 = np[0], q1 = np[1], q2 = np[2], q3 = np[3], q4 = np[4];
        int idx[11] = {xw, q0.x, q0.y, q1.x, q1.y, q2.x, q2.y, q3.x, q3.y, q4.x, q4.y};

        // center row -> 32 floats (tail half masked for lanes >= 3)
        uint4 cm = inM[(size_t)cw * 16 + lane];
        uint4 ct = inT[(size_t)cw * 4 + tl];
        float cf[32];
        unp16(cm, cf);
        unp16(ct, cf + 16);
        #pragma unroll
        for (int j = 16; j < 32; ++j) cf[j] *= tmask;

        // PD-deep pipelined gather+dot over the 11 score rows
        float part[11];
        uint4 bm[PD], bt[PD];
        #pragma unroll
        for (int j = 0; j < PD - 1; ++j) {
            bm[j] = outM[(size_t)idx[j] * 16 + lane];
            bt[j] = outT[(size_t)idx[j] * 4 + tl];
        }
        #pragma unroll
        for (int j = 0; j < 11; ++j) {
            if (j + PD - 1 < 11) {
                bm[(j + PD - 1) % PD] = outM[(size_t)idx[j + PD - 1] * 16 + lane];
                bt[(j + PD - 1) % PD] = outT[(size_t)idx[j + PD - 1] * 4 + tl];
            }
            part[j] = dqf(cf, bm[j % PD]) + dqf(cf + 16, bt[j % PD]);
        }

        #pragma unroll
        for (int j = 0; j < 11; ++j) part[j] = reduce16(part[j]);

        float loss = lsig(part[0]);
        #pragma unroll
        for (int j = 1; j < 11; ++j) loss += lsig(-part[j]);

        tsum += (lane == 0) ? loss : 0.0f;
    }

    float w = tsum;
    #pragma unroll
    for (int m = 1; m < 64; m <<= 1) w += __shfl_xor(w, m);

    __shared__ double ssum[4];
    const int wid = threadIdx.x >> 6;
    if ((threadIdx.x & 63) == 0) ssum[wid] = (double)w;
    __syncthreads();
    if (threadIdx.x == 0) {
        atomicAdd(acc, ssum[0] + ssum[1] + ssum[2] + ssum[3]);
    }
}

// ---------- f32 fallback (proven) ----------

__global__ __launch_bounds__(256) void sgns_f32(
    const int* __restrict__ center_words,
    const int* __restrict__ context_words,
    const int* __restrict__ neg_samples,
    const float* __restrict__ in_embed,
    const float* __restrict__ out_embed,
    double* __restrict__ acc)
{
    const int lane = threadIdx.x & 15;
    const int group = (blockIdx.x * blockDim.x + threadIdx.x) >> 4;
    const int nGroups = (gridDim.x * blockDim.x) >> 4;

    const float4* inE = reinterpret_cast<const float4*>(in_embed);
    const float4* outE = reinterpret_cast<const float4*>(out_embed);
    const int RU = EMBED / 4;
    const int TAIL = RU - 64;

    float tsum = 0.0f;

    for (int b = group; b < BATCH; b += nGroups) {
        const int c = center_words[b];
        const int ctx = context_words[b];

        const float4* crow = inE + (size_t)c * RU;
        float4 c0 = crow[lane + 0];
        float4 c1 = crow[lane + 16];
        float4 c2 = crow[lane + 32];
        float4 c3 = crow[lane + 48];
        float4 c4 = make_float4(0.f, 0.f, 0.f, 0.f);
        if (lane < TAIL) c4 = crow[lane + 64];

        const float4* xrow = outE + (size_t)ctx * RU;
        float p = dot4(c0, xrow[lane + 0])
                + dot4(c1, xrow[lane + 16])
                + dot4(c2, xrow[lane + 32])
                + dot4(c3, xrow[lane + 48]);
        if (lane < TAIL) p += dot4(c4, xrow[lane + 64]);
        p = reduce16(p);

        float loss = lsig(p);

        #pragma unroll
        for (int k = 0; k < NEG; ++k) {
            const int nk = neg_samples[b * NEG + k];
            const float4* nrow = outE + (size_t)nk * RU;
            float s = dot4(c0, nrow[lane + 0])
                    + dot4(c1, nrow[lane + 16])
                    + dot4(c2, nrow[lane + 32])
                    + dot4(c3, nrow[lane + 48]);
            if (lane < TAIL) s += dot4(c4, nrow[lane + 64]);
            s = reduce16(s);
            loss += lsig(-s);
        }

        tsum += (lane == 0) ? loss : 0.0f;
    }

    float w = tsum;
    #pragma unroll
    for (int m = 1; m < 64; m <<= 1) w += __shfl_xor(w, m);

    __shared__ double ssum[4];
    const int wid = threadIdx.x >> 6;
    if ((threadIdx.x & 63) == 0) ssum[wid] = (double)w;
    __syncthreads();
    if (threadIdx.x == 0) {
        atomicAdd(acc, ssum[0] + ssum[1] + ssum[2] + ssum[3]);
    }
}

// ---------- launch ----------

extern "C" void kernel_launch(void* const* d_in, const int* in_sizes, int n_in,
                              void* d_out, int out_size, void* d_ws, size_t ws_size,
                              hipStream_t stream) {
    const int* center = (const int*)d_in[0];
    const int* context = (const int*)d_in[1];
    const int* negs = (const int*)d_in[2];
    const float* inE = (const float*)d_in[3];
    const float* outE = (const float*)d_in[4];
    float* out = (float*)d_out;
    double* acc = (double*)d_ws;

    sgns_zero_acc<<<1, 1, 0, stream>>>(acc);

    const size_t MAIN_B = (size_t)VOCABN * 16 * 16;  // 25,600,000 per table
    const size_t TAIL_B = (size_t)VOCABN * 4 * 16;   //  6,400,000 per table
    const size_t need = 256 + 2 * (MAIN_B + TAIL_B); // 64,000,256

    if (ws_size >= need) {
        char* base = (char*)d_ws + 256;
        uint4* inM  = (uint4*)(base);
        uint4* inT  = (uint4*)(base + MAIN_B);
        uint4* outM = (uint4*)(base + MAIN_B + TAIL_B);
        uint4* outT = (uint4*)(base + 2 * MAIN_B + TAIL_B);
        cvt_fp8s<<<4096, 256, 0, stream>>>(inE, inM, inT, VOCABN);
        cvt_fp8s<<<4096, 256, 0, stream>>>(outE, outM, outT, VOCABN);
        // 2048 blocks -> 32768 groups, 4 batch elems each (r4-proven config)
        sgns_fp8<<<2048, 256, 0, stream>>>(center, context, negs,
                                           inM, inT, outM, outT, acc);
    } else {
        sgns_f32<<<2048, 256, 0, stream>>>(center, context, negs, inE, outE, acc);
    }

    sgns_finalize<<<1, 1, 0, stream>>>(acc, out);
}